// Round 1
// baseline (105.828 us; speedup 1.0000x reference)
//
#include <hip/hip_runtime.h>
#include <hip/hip_bf16.h>
#include <stdint.h>

#define NASSETS 512
#define WINDOW  256
#define NBATCH  32
#define NWORDS  16      // 512 bits / 32
#define TILE    64
#define APAD    40      // LDS row stride (bf16 units) for A/B tiles: 32 data + 8 pad
#define CPAD    65      // LDS row stride (floats) for C tile

typedef __attribute__((ext_vector_type(4))) float floatx4;
typedef __attribute__((ext_vector_type(8))) short shortx8;

__device__ __forceinline__ unsigned short f2bf(float f) {
    union { float f; unsigned int u; } c; c.f = f;
    unsigned int u = c.u;
    unsigned int r = (u + 0x7FFFu + ((u >> 16) & 1u)) >> 16;  // RNE
    return (unsigned short)r;
}

// Kernel 1: per-(b,asset) column stats over W, write normalized transposed bf16 Xt[b][n][w]
__global__ __launch_bounds__(256)
void normalize_kernel(const float* __restrict__ ret, short* __restrict__ Xt) {
    int tid = blockIdx.x * blockDim.x + threadIdx.x;   // b*NASSETS + n
    int b = tid >> 9;
    int n = tid & (NASSETS - 1);
    const float* col = ret + (size_t)b * WINDOW * NASSETS + n;

    double s = 0.0, ss = 0.0;
    for (int w = 0; w < WINDOW; ++w) {
        float x = col[(size_t)w * NASSETS];
        s += (double)x;
        ss += (double)x * (double)x;
    }
    double mean = s / (double)WINDOW;
    double var  = (ss - (double)WINDOW * mean * mean) / (double)(WINDOW - 1);
    if (var < 0.0) var = 0.0;
    double stdv = sqrt(var) + 1e-8;   // torch-style: std(centered, ddof=1) + 1e-8
    float inv = (float)(1.0 / stdv);
    float mf  = (float)mean;

    short* orow = Xt + (size_t)(b * NASSETS + n) * WINDOW;
    for (int w0 = 0; w0 < WINDOW; w0 += 8) {
        shortx8 pack;
#pragma unroll
        for (int j = 0; j < 8; ++j) {
            float x = col[(size_t)(w0 + j) * NASSETS];
            pack[j] = (short)f2bf((x - mf) * inv);
        }
        *(shortx8*)(orow + w0) = pack;
    }
}

// Kernel 2: 64x64 corr tile per block via MFMA bf16, fused threshold -> bit-pack (3 thresholds)
// grid: (N/64 jtiles, N/64 itiles, B), block 256 (4 waves, 2x2 arrangement of 32x32 per wave)
__global__ __launch_bounds__(256)
void corr_adj_kernel(const short* __restrict__ Xt, unsigned int* __restrict__ adj) {
    __shared__ short lsA[TILE * APAD];
    __shared__ short lsB[TILE * APAD];
    __shared__ float lsC[TILE * CPAD];

    int b  = blockIdx.z;
    int i0 = blockIdx.y * TILE;
    int j0 = blockIdx.x * TILE;
    int t    = threadIdx.x;
    int lane = t & 63;
    int wave = t >> 6;
    int wi = wave >> 1, wj = wave & 1;

    const short* base = Xt + (size_t)b * NASSETS * WINDOW;

    floatx4 acc[2][2] = {};

    int ldRow = t >> 2;          // 0..63
    int ldSeg = (t & 3) * 8;     // bf16 offset within 32-wide k chunk

    int q = lane >> 4;           // quad 0..3
    int m = lane & 15;

    for (int k0 = 0; k0 < WINDOW; k0 += 32) {
        shortx8 va = *(const shortx8*)(base + (size_t)(i0 + ldRow) * WINDOW + k0 + ldSeg);
        shortx8 vb = *(const shortx8*)(base + (size_t)(j0 + ldRow) * WINDOW + k0 + ldSeg);
        __syncthreads();   // previous iteration's LDS reads complete
        *(shortx8*)(lsA + ldRow * APAD + ldSeg) = va;
        *(shortx8*)(lsB + ldRow * APAD + ldSeg) = vb;
        __syncthreads();

        shortx8 afrag[2], bfrag[2];
#pragma unroll
        for (int mi = 0; mi < 2; ++mi)
            afrag[mi] = *(const shortx8*)(lsA + (wi * 32 + mi * 16 + m) * APAD + q * 8);
#pragma unroll
        for (int nj = 0; nj < 2; ++nj)
            bfrag[nj] = *(const shortx8*)(lsB + (wj * 32 + nj * 16 + m) * APAD + q * 8);
#pragma unroll
        for (int mi = 0; mi < 2; ++mi)
#pragma unroll
            for (int nj = 0; nj < 2; ++nj)
                acc[mi][nj] = __builtin_amdgcn_mfma_f32_16x16x32_bf16(
                    afrag[mi], bfrag[nj], acc[mi][nj], 0, 0, 0);
    }

    // C/D layout (m89/m91): col = lane&15, row = quad*4 + reg
#pragma unroll
    for (int mi = 0; mi < 2; ++mi)
#pragma unroll
        for (int nj = 0; nj < 2; ++nj)
#pragma unroll
            for (int r = 0; r < 4; ++r) {
                int row = wi * 32 + mi * 16 + q * 4 + r;
                int col = wj * 32 + nj * 16 + m;
                lsC[row * CPAD + col] = acc[mi][nj][r];
            }
    __syncthreads();

    // pack bits: 128 threads, each (row, 32-col word); compare |dot| > t*W (corr = dot/W)
    if (t < 128) {
        int row  = t >> 1;
        int word = t & 1;
        int gi = i0 + row;
        const float T0 = 0.3f * (float)WINDOW;
        const float T1 = 0.5f * (float)WINDOW;
        const float T2 = 0.7f * (float)WINDOW;
        unsigned int w0 = 0, w1 = 0, w2 = 0;
#pragma unroll
        for (int c = 0; c < 32; ++c) {
            int gj = j0 + word * 32 + c;
            float v = fabsf(lsC[row * CPAD + word * 32 + c]);
            if (gi != gj) {   // zero diagonal
                if (v > T0) w0 |= 1u << c;
                if (v > T1) w1 |= 1u << c;
                if (v > T2) w2 |= 1u << c;
            }
        }
        int wordIdx = (j0 >> 5) + word;
        size_t stride_t = (size_t)NBATCH * NASSETS * NWORDS;
        size_t rb = ((size_t)b * NASSETS + gi) * NWORDS + wordIdx;
        adj[rb]                = w0;
        adj[rb + stride_t]     = w1;
        adj[rb + 2 * stride_t] = w2;
    }
}

// Kernel 3: connected components (min-label propagation + pointer jumping) + edge count
// grid: (3 thresholds, B), block 512 (one thread per node)
__global__ __launch_bounds__(512)
void betti_kernel(const unsigned int* __restrict__ adj, float* __restrict__ out) {
    __shared__ int lab[NASSETS];
    __shared__ int changed;
    __shared__ int red[8];

    int th = blockIdx.x;
    int b  = blockIdx.y;
    int i  = threadIdx.x;
    int lane = i & 63, wv = i >> 6;

    const unsigned int* rowp =
        adj + (((size_t)th * NBATCH + b) * NASSETS + i) * NWORDS;
    unsigned int row[NWORDS];
    int deg = 0;
#pragma unroll
    for (int w = 0; w < NWORDS; ++w) {
        row[w] = rowp[w];
        deg += __popc(row[w]);
    }

    // edge-count reduction (sum of degrees = 2*edges)
    int v = deg;
#pragma unroll
    for (int off = 32; off > 0; off >>= 1) v += __shfl_down(v, off);
    if (lane == 0) red[wv] = v;
    lab[i] = i;
    __syncthreads();
    int total_deg = 0;
    if (i == 0)
        for (int k = 0; k < 8; ++k) total_deg += red[k];

    // min-label propagation with pointer jumping; monotone -> terminates
    for (;;) {
        __syncthreads();                 // A: prior reads of `changed` done
        if (i == 0) changed = 0;
        __syncthreads();                 // B: reset visible; prior lab writes visible
        int mlab = lab[i];
#pragma unroll
        for (int w = 0; w < NWORDS; ++w) {
            unsigned int bits = row[w];
            int basej = w * 32;
            while (bits) {
                int j = basej + __builtin_ctz(bits);
                bits &= bits - 1;
                int lj = lab[j];
                if (lj < mlab) mlab = lj;
            }
        }
        int lm = lab[mlab];              // pointer-jump
        if (lm < mlab) mlab = lm;
        __syncthreads();                 // C: all reads done before writes
        if (mlab < lab[i]) { lab[i] = mlab; changed = 1; }
        __syncthreads();                 // D: writes visible
        if (!changed) break;             // uniform
    }

    // component representatives: lab[i] == i
    int isrep = (lab[i] == i) ? 1 : 0;
#pragma unroll
    for (int off = 32; off > 0; off >>= 1) isrep += __shfl_down(isrep, off);
    if (lane == 0) red[wv] = isrep;
    __syncthreads();
    if (i == 0) {
        int comps = 0;
        for (int k = 0; k < 8; ++k) comps += red[k];
        float compf = (float)comps;
        float edges = (float)total_deg * 0.5f;
        float b0 = compf / (float)NASSETS;
        float b1 = fmaxf(0.0f, edges - (float)NASSETS + compf) / (float)NASSETS;
        out[b * 6 + th * 2 + 0] = b0;
        out[b * 6 + th * 2 + 1] = b1;
    }
}

extern "C" void kernel_launch(void* const* d_in, const int* in_sizes, int n_in,
                              void* d_out, int out_size, void* d_ws, size_t ws_size,
                              hipStream_t stream) {
    const float* ret = (const float*)d_in[0];
    float* out = (float*)d_out;
    char* ws = (char*)d_ws;

    short* Xt = (short*)ws;                                       // 32*512*256*2 = 8 MB
    unsigned int* adj =
        (unsigned int*)(ws + (size_t)NBATCH * NASSETS * WINDOW * sizeof(short)); // 3 MB

    normalize_kernel<<<(NBATCH * NASSETS) / 256, 256, 0, stream>>>(ret, Xt);

    dim3 g2(NASSETS / TILE, NASSETS / TILE, NBATCH);
    corr_adj_kernel<<<g2, 256, 0, stream>>>(Xt, adj);

    dim3 g3(3, NBATCH);
    betti_kernel<<<g3, 512, 0, stream>>>(adj, out);
}